// Round 14
// baseline (558.952 us; speedup 1.0000x reference)
//
#include <hip/hip_runtime.h>
#include <hip/hip_bf16.h>

// ---------------------------------------------------------------------------
// EdgePredModel: NodeMLP + 2x GATv2 + EdgeMLP.
// R14: edge_mlp9 (512-thr block, 8 waves, TJ=4 -> 2x occupancy);
//      gat 4-edge ILP; scatter||x-fc and gat1||fc2 dispatch merges.
// ---------------------------------------------------------------------------
constexpr int N_NODES = 20000;
constexpr int N_EDGES = 320000;

typedef _Float16 half8 __attribute__((ext_vector_type(8)));
typedef _Float16 half4 __attribute__((ext_vector_type(4)));
typedef float    f32x16 __attribute__((ext_vector_type(16)));

__device__ __forceinline__ float lrelu(float x) { return x > 0.f ? x : 0.2f * x; }

// ------------------------------ CSR build ---------------------------------
// single-block exclusive scan of 20000 counts -> row_off, cursor
__global__ void scan_all_kernel(const int* __restrict__ counts,
                                int* __restrict__ row_off, int* __restrict__ cursor) {
    __shared__ int ps[1024];
    const int t = threadIdx.x;
    const int base = t * 20;
    int loc[20];
    int sum = 0;
#pragma unroll
    for (int i = 0; i < 20; ++i) {
        const int idx = base + i;
        const int v = (idx < N_NODES) ? counts[idx] : 0;
        loc[i] = sum;
        sum += v;
    }
    ps[t] = sum;
    __syncthreads();
    for (int off = 1; off < 1024; off <<= 1) {
        const int v = (t >= off) ? ps[t - off] : 0;
        __syncthreads();
        ps[t] += v;
        __syncthreads();
    }
    const int ex = ps[t] - sum;     // exclusive prefix of this thread's chunk
#pragma unroll
    for (int i = 0; i < 20; ++i) {
        const int idx = base + i;
        if (idx < N_NODES) {
            row_off[idx] = ex + loc[i];
            cursor[idx]  = ex + loc[i];
        }
    }
    if (t == 0) row_off[N_NODES] = N_EDGES;
}

// --------------------- W prepack into B-fragments (hi only) ----------------
template <int K, int M>
__device__ __forceinline__ void pack_one(int idx, const float* __restrict__ W,
                                         int r1, int k1, int r2, int joff, int ldw,
                                         _Float16* __restrict__ H) {
    const int l  = idx & 63;
    const int t  = (idx >> 6) % (M / 32);
    const int s  = (idx >> 6) / (M / 32);
    const int j  = joff + t * 32 + (l & 31);
    const int kb = s * 16 + (l >> 5) * 8;
    half8 vh;
#pragma unroll
    for (int i = 0; i < 8; ++i) {
        const int k    = kb + i;
        const int rrow = (k < k1) ? (r1 + k) : (r2 + (k - k1));
        vh[i] = (_Float16)W[(size_t)rrow * ldw + j];
    }
    reinterpret_cast<half8*>(H)[idx] = vh;
}

// segment offsets in half8 units
constexpr int OFF_W1  = 0;        // ew1  512x256 -> 16384
constexpr int OFF_G2S = 16384;    // g2ws 256x256 ->  8192
constexpr int OFF_G2D = 24576;    // g2wd
constexpr int OFF_SW0 = 32768;    // ew0-S cols 0-255 -> 12288
constexpr int OFF_SW1 = 45056;
constexpr int OFF_DW0 = 57344;
constexpr int OFF_DW1 = 69632;
constexpr int OFF_N1  = 81920;    // nw1 128x128 -> 2048
constexpr int OFF_X   = 83968;    // 5 x 1024: nw0 | g1ws(2 segs) | g1wd(2 segs)
constexpr int PACK_TOT = 89088;   // total half8
constexpr int PACK_BLK = (PACK_TOT + 255) / 256;   // 348
constexpr int HIST_BLK = 1250;

struct PackIn {
    const float *ew1, *g1ws, *g1wd, *g2ws, *g2wd, *ew0, *nw0, *nw1;
    _Float16 *H;
    const int* dst;
    int* counts;
};

// merged: blocks [0,HIST_BLK) do dst-histogram; rest do weight prepack
__global__ void hist_prepack_kernel(PackIn a) {
    if (blockIdx.x < HIST_BLK) {
        const int e = blockIdx.x * 256 + threadIdx.x;
        if (e < N_EDGES) atomicAdd(&a.counts[a.dst[e]], 1);
        return;
    }
    const int idx = (blockIdx.x - HIST_BLK) * 256 + threadIdx.x;
    if (idx >= PACK_TOT) return;
    _Float16* H = a.H;
    if (idx < OFF_G2S)
        pack_one<512, 256>(idx - OFF_W1, a.ew1, 0, 512, 0, 0, 256, H + OFF_W1 * 8);
    else if (idx < OFF_G2D)
        pack_one<256, 256>(idx - OFF_G2S, a.g2ws, 0, 256, 0, 0, 256, H + OFF_G2S * 8);
    else if (idx < OFF_SW0)
        pack_one<256, 256>(idx - OFF_G2D, a.g2wd, 0, 256, 0, 0, 256, H + OFF_G2D * 8);
    else if (idx < OFF_SW1)
        pack_one<384, 256>(idx - OFF_SW0, a.ew0, 0, 128, 256, 0, 512, H + OFF_SW0 * 8);
    else if (idx < OFF_DW0)
        pack_one<384, 256>(idx - OFF_SW1, a.ew0, 0, 128, 256, 256, 512, H + OFF_SW1 * 8);
    else if (idx < OFF_DW1)
        pack_one<384, 256>(idx - OFF_DW0, a.ew0, 128, 128, 512, 0, 512, H + OFF_DW0 * 8);
    else if (idx < OFF_N1)
        pack_one<384, 256>(idx - OFF_DW1, a.ew0, 128, 128, 512, 256, 512, H + OFF_DW1 * 8);
    else if (idx < OFF_X)
        pack_one<128, 128>(idx - OFF_N1, a.nw1, 0, 128, 0, 0, 128, H + OFF_N1 * 8);
    else {
        const int xi  = idx - OFF_X;
        const int seg = xi >> 10, r = xi & 1023;
        const int sb  = OFF_X + seg * 1024;
        if (seg == 0)
            pack_one<64, 128>(r, a.nw0, 0, 64, 0, 0, 128, H + sb * 8);
        else if (seg <= 2)
            pack_one<64, 128>(r, a.g1ws, 0, 64, 0, (seg - 1) * 128, 256, H + sb * 8);
        else
            pack_one<64, 128>(r, a.g1wd, 0, 64, 0, (seg - 3) * 128, 256, H + sb * 8);
    }
}

// ----------------------- split-fp16 MFMA node linear -----------------------
// 2-product: y = (xh + xl) @ Wh. Per-jb outputs fp32 y and/or fp16 yh.
struct LinOut { float* y[6]; const float* b[6]; _Float16* yh[6]; int ldy[6]; int relu[6]; };

template <int K, int TJ, int WR, int K1, int LD1, int LD2, int SEG>
__device__ __forceinline__ void linear_body(
    int bx, int jb,
    const float* __restrict__ X1, const float* __restrict__ X2,
    const _Float16* __restrict__ BHp, const LinOut& lo, int N) {
    constexpr int WC    = 4 / WR;
    constexpr int TILES = WC * TJ;
    const int tid = threadIdx.x;
    const int wv  = tid >> 6, l = tid & 63;
    const int rg  = (WR == 1) ? 0 : ((WR == 4) ? wv : (wv & 1));
    const int cg  = (WR == 1) ? wv : ((WR == 4) ? 0 : (wv >> 1));
    const int m   = l & 31, h = l >> 5;
    const int row = bx * (32 * WR) + rg * 32 + m;
    const int ar  = (row < N) ? row : (N - 1);
    const float* __restrict__ xr1 = X1 + (size_t)ar * LD1;
    const float* __restrict__ xr2 = X2 + (size_t)ar * LD2;
    const half8* __restrict__ BH = reinterpret_cast<const half8*>(BHp) + (size_t)jb * SEG;
    const float* __restrict__ bp = lo.b[jb];
    float* __restrict__ Y = lo.y[jb];
    _Float16* __restrict__ Yh = lo.yh[jb];
    const int ldy = lo.ldy[jb];
    const int rel = lo.relu[jb];

    f32x16 acc[TJ];
#pragma unroll
    for (int jt = 0; jt < TJ; ++jt) {
        const float bv = bp ? bp[cg * TJ * 32 + jt * 32 + m] : 0.f;
#pragma unroll
        for (int r = 0; r < 16; ++r) acc[jt][r] = bv;
    }

    const int kf = h * 8;
    const float* pf = (kf < K1) ? (xr1 + kf) : (xr2 + (kf - K1));
    float4 xa = *reinterpret_cast<const float4*>(pf);
    float4 xb = *reinterpret_cast<const float4*>(pf + 4);

    for (int s = 0; s < K / 16; ++s) {
        const float xs[8] = {xa.x, xa.y, xa.z, xa.w, xb.x, xb.y, xb.z, xb.w};
        if (s + 1 < K / 16) {
            const int kn = (s + 1) * 16 + h * 8;
            const float* pn = (kn < K1) ? (xr1 + kn) : (xr2 + (kn - K1));
            xa = *reinterpret_cast<const float4*>(pn);
            xb = *reinterpret_cast<const float4*>(pn + 4);
        }
        half8 ah, al;
#pragma unroll
        for (int i = 0; i < 8; ++i) {
            const _Float16 hi = (_Float16)xs[i];
            ah[i] = hi;
            al[i] = (_Float16)(xs[i] - (float)hi);
        }
#pragma unroll
        for (int jt = 0; jt < TJ; ++jt) {
            const int fi = (s * TILES + cg * TJ + jt) * 64 + l;
            const half8 bh = BH[fi];
            acc[jt] = __builtin_amdgcn_mfma_f32_32x32x16_f16(ah, bh, acc[jt], 0, 0, 0);
            acc[jt] = __builtin_amdgcn_mfma_f32_32x32x16_f16(al, bh, acc[jt], 0, 0, 0);
        }
    }

    const int rbase = bx * (32 * WR) + rg * 32;
#pragma unroll
    for (int jt = 0; jt < TJ; ++jt) {
        const int j = cg * TJ * 32 + jt * 32 + m;
#pragma unroll
        for (int r = 0; r < 16; ++r) {
            const int orow = rbase + (r & 3) + 8 * (r >> 2) + 4 * h;
            if (orow < N) {
                float v = acc[jt][r];
                if (rel) v = fmaxf(v, 0.f);
                if (Y)  Y[(size_t)orow * ldy + j] = v;
                if (Yh) Yh[(size_t)orow * ldy + j] = (_Float16)v;
            }
        }
    }
}

template <int K, int TJ, int WR, int K1, int LD1, int LD2, int MINW, int SEG>
__global__ __launch_bounds__(256, MINW) void mfma_linear2_kernel(
    const float* __restrict__ X1, const float* __restrict__ X2,
    const _Float16* __restrict__ BHp, LinOut lo, int N) {
    linear_body<K, TJ, WR, K1, LD1, LD2, SEG>(blockIdx.x, blockIdx.y, X1, X2, BHp, lo, N);
}

// --------------------------- fused GATv2 layer -----------------------------
// No online max (logits bounded); 4-edge ILP pipeline.
__device__ __forceinline__ void gat_body(int n, const _Float16* __restrict__ fsh,
                                         const float* __restrict__ fd,
                                         const float* __restrict__ attn,
                                         const int* __restrict__ row_off,
                                         const int* __restrict__ srcs,
                                         float* __restrict__ outp) {
    const int l = threadIdx.x & 63;
    const int base = (l >> 5) * 128 + (l & 31) * 4;    // h*128 + d
    const float4 fdv = *reinterpret_cast<const float4*>(&fd[n * 256 + base]);
    const float4 av  = *reinterpret_cast<const float4*>(&attn[base]);
    const int s0 = row_off[n], s1 = row_off[n + 1];

    auto LD = [&](int k) {
        return *reinterpret_cast<const half4*>(&fsh[(size_t)srcs[k] * 256 + base]);
    };
    auto LOGIT = [&](const float4& v) {
        float p = lrelu(v.x + fdv.x) * av.x;
        p = fmaf(lrelu(v.y + fdv.y), av.y, p);
        p = fmaf(lrelu(v.z + fdv.z), av.z, p);
        p = fmaf(lrelu(v.w + fdv.w), av.w, p);
        return p;
    };

    float lsum = 0.f;
    float4 acc = {0.f, 0.f, 0.f, 0.f};
    half4 c[4], nx[4];
#pragma unroll
    for (int k = 0; k < 4; ++k) { c[k] = half4{0, 0, 0, 0}; nx[k] = half4{0, 0, 0, 0}; }
    int i = s0;
#pragma unroll
    for (int k = 0; k < 4; ++k) if (i + k < s1) c[k] = LD(i + k);
#pragma unroll
    for (int k = 0; k < 4; ++k) if (i + 4 + k < s1) nx[k] = LD(i + 4 + k);

    for (; i + 3 < s1; i += 4) {
        float4 v[4];
#pragma unroll
        for (int k = 0; k < 4; ++k)
            v[k] = float4{(float)c[k].x, (float)c[k].y, (float)c[k].z, (float)c[k].w};
#pragma unroll
        for (int k = 0; k < 4; ++k) {
            c[k] = nx[k];
            if (i + 8 + k < s1) nx[k] = LD(i + 8 + k);
        }
        float p[4];
#pragma unroll
        for (int k = 0; k < 4; ++k) p[k] = LOGIT(v[k]);
#pragma unroll
        for (int off = 1; off < 32; off <<= 1)
#pragma unroll
            for (int k = 0; k < 4; ++k) p[k] += __shfl_xor(p[k], off);
        float w[4];
#pragma unroll
        for (int k = 0; k < 4; ++k) w[k] = __expf(p[k]);
        lsum += (w[0] + w[1]) + (w[2] + w[3]);
#pragma unroll
        for (int k = 0; k < 4; ++k) {
            acc.x = fmaf(w[k], v[k].x, acc.x);
            acc.y = fmaf(w[k], v[k].y, acc.y);
            acc.z = fmaf(w[k], v[k].z, acc.z);
            acc.w = fmaf(w[k], v[k].w, acc.w);
        }
    }
    for (int k = 0; i < s1; ++i, ++k) {                  // tail (0..3 edges, in c[])
        const float4 v = {(float)c[k].x, (float)c[k].y, (float)c[k].z, (float)c[k].w};
        float p = LOGIT(v);
#pragma unroll
        for (int off = 1; off < 32; off <<= 1) p += __shfl_xor(p, off);
        const float w = __expf(p);
        lsum += w;
        acc.x = fmaf(w, v.x, acc.x);
        acc.y = fmaf(w, v.y, acc.y);
        acc.z = fmaf(w, v.z, acc.z);
        acc.w = fmaf(w, v.w, acc.w);
    }
    const float inv = (s1 > s0) ? 1.f / lsum : 0.f;
    float4 o;
    o.x = fmaxf(acc.x * inv, 0.f);
    o.y = fmaxf(acc.y * inv, 0.f);
    o.z = fmaxf(acc.z * inv, 0.f);
    o.w = fmaxf(acc.w * inv, 0.f);
    *reinterpret_cast<float4*>(&outp[n * 256 + base]) = o;
}

__global__ __launch_bounds__(256, 4) void gat_fused_kernel(
    const _Float16* __restrict__ fsh, const float* __restrict__ fd,
    const float* __restrict__ attn, const int* __restrict__ row_off,
    const int* __restrict__ srcs, float* __restrict__ outp) {
    const int n = blockIdx.x * 4 + (threadIdx.x >> 6);
    if (n < N_NODES) gat_body(n, fsh, fd, attn, row_off, srcs, outp);
}

// ---------------- merged: scatter (CSR) || x-fc (5 segments) ---------------
__global__ __launch_bounds__(256, 4) void scatter_xfc_kernel(
    const int* __restrict__ src, const int* __restrict__ dst,
    int* __restrict__ cursor, int* __restrict__ eidx, int* __restrict__ srcs,
    const float* __restrict__ x, const _Float16* __restrict__ BH, LinOut lo) {
    if (blockIdx.x < 1250) {
        const int e = blockIdx.x * 256 + threadIdx.x;
        if (e < N_EDGES) {
            const int p = atomicAdd(&cursor[dst[e]], 1);
            eidx[p] = e;
            srcs[p] = src[e];
        }
        return;
    }
    const int bx = blockIdx.x - 1250;                 // [0, 3125)
    linear_body<64, 1, 1, 64, 64, 64, 1024>(bx % 625, bx / 625, x, x, BH, lo, N_NODES);
}

// ---------------- merged: GAT layer-1 || NodeMLP fc2 -----------------------
__global__ __launch_bounds__(256, 4) void gat1_fc2_kernel(
    const _Float16* __restrict__ fsh, const float* __restrict__ fd,
    const float* __restrict__ attn, const int* __restrict__ row_off,
    const int* __restrict__ srcs, float* __restrict__ outp,
    const float* __restrict__ fsb, const _Float16* __restrict__ BHn1, LinOut lo2) {
    if (blockIdx.x < 5000) {
        const int n = blockIdx.x * 4 + (threadIdx.x >> 6);
        if (n < N_NODES) gat_body(n, fsh, fd, attn, row_off, srcs, outp);
        return;
    }
    linear_body<128, 1, 1, 128, 128, 128, 0>(blockIdx.x - 5000, 0, fsb, fsb, BHn1,
                                             lo2, N_NODES);
}

// ------------------------------ fused EdgeMLP v9 ---------------------------
// 512-thread block (8 waves = 4 e-groups x 2 j-groups), 128 edges/block.
// TJ=4 -> acc 64 AGPR -> 4 waves/SIMD (2x occupancy vs mlp7). B hi staged
// per step into 2x8KB LDS (each wave stages 1 of 8 chunks); fp16 S/D gather;
// single-product MFMA; cross-jg combine via 1 KB LDS.
__global__ __launch_bounds__(512, 4) void edge_mlp9_kernel(
    const _Float16* __restrict__ S, const _Float16* __restrict__ Dn,
    const int* __restrict__ srcs, const int* __restrict__ eidx,
    const int* __restrict__ dstf,
    const _Float16* __restrict__ WpH,
    const float* __restrict__ b1, const float* __restrict__ w2,
    const float* __restrict__ b2, float* __restrict__ out) {
    __shared__ __align__(16) _Float16 Bs[2][8][512];   // 16 KB
    __shared__ float q[2][128];                         // 1 KB
    const int tid = threadIdx.x;
    const int wv  = tid >> 6, l = tid & 63;
    const int eg  = wv & 3, jg = wv >> 2;
    const int m   = l & 31, h = l >> 5;
    const int e0  = blockIdx.x * 128;
    const int slot = e0 + eg * 32 + m;
    const _Float16* __restrict__ Srow = S  + (size_t)srcs[slot] * 512;
    const _Float16* __restrict__ Drow = Dn + (size_t)dstf[eidx[slot]] * 512;

    f32x16 acc[4];
#pragma unroll
    for (int jt = 0; jt < 4; ++jt) {
        const float bv = b1[jg * 128 + jt * 32 + m];
#pragma unroll
        for (int r = 0; r < 16; ++r) acc[jt][r] = bv;
    }

    // stage B(s=0) hi into buf 0: wave wv stages chunk wv
    *reinterpret_cast<float4*>(&Bs[0][wv][l * 8]) =
        *reinterpret_cast<const float4*>(WpH + ((size_t)wv * 64 + l) * 8);
    half8 sv = *reinterpret_cast<const half8*>(Srow + h * 8);
    half8 dv = *reinterpret_cast<const half8*>(Drow + h * 8);
    __syncthreads();

    for (int s = 0; s < 32; ++s) {
        const int buf = s & 1;
        float4 bst;
        if (s < 31)
            bst = *reinterpret_cast<const float4*>(
                WpH + ((size_t)((s + 1) * 8 + wv) * 64 + l) * 8);
        half8 xh;
#pragma unroll
        for (int i = 0; i < 8; ++i) {
            const _Float16 t = sv[i] + dv[i];
            xh[i] = t > (_Float16)0.f ? t : (_Float16)0.f;
        }
        if (s < 31) {
            const int ko = (s + 1) * 16 + h * 8;
            sv = *reinterpret_cast<const half8*>(Srow + ko);
            dv = *reinterpret_cast<const half8*>(Drow + ko);
        }
#pragma unroll
        for (int jt = 0; jt < 4; ++jt) {
            const half8 bh = *reinterpret_cast<const half8*>(&Bs[buf][jg * 4 + jt][l * 8]);
            acc[jt] = __builtin_amdgcn_mfma_f32_32x32x16_f16(xh, bh, acc[jt], 0, 0, 0);
        }
        if (s < 31)
            *reinterpret_cast<float4*>(&Bs[buf ^ 1][wv][l * 8]) = bst;
        __syncthreads();
    }

    // ---- layer-2 fold + 32-lane reduce + cross-jg combine + scatter store ----
    float part[16];
#pragma unroll
    for (int r = 0; r < 16; ++r) part[r] = 0.f;
#pragma unroll
    for (int jt = 0; jt < 4; ++jt) {
        const float w2v = w2[jg * 128 + jt * 32 + m];
#pragma unroll
        for (int r = 0; r < 16; ++r)
            part[r] = fmaf(fmaxf(acc[jt][r], 0.f), w2v, part[r]);
    }
#pragma unroll
    for (int off = 1; off < 32; off <<= 1)
#pragma unroll
        for (int r = 0; r < 16; ++r) part[r] += __shfl_xor(part[r], off);
    if (m == 0) {
#pragma unroll
        for (int r = 0; r < 16; ++r) {
            const int row = (r & 3) + 8 * (r >> 2) + 4 * h;
            q[jg][eg * 32 + row] = part[r];
        }
    }
    __syncthreads();
    if (tid < 128) out[eidx[e0 + tid]] = q[0][tid] + q[1][tid] + b2[0];
}

// ------------------------------ launch ------------------------------------
extern "C" void kernel_launch(void* const* d_in, const int* in_sizes, int n_in,
                              void* d_out, int out_size, void* d_ws, size_t ws_size,
                              hipStream_t stream) {
    (void)in_sizes; (void)n_in; (void)out_size; (void)ws_size;
    const float* x    = (const float*)d_in[0];
    const int*   src  = (const int*)d_in[1];
    const int*   dst  = (const int*)d_in[2];
    const float* nw0  = (const float*)d_in[3];
    const float* nb0  = (const float*)d_in[4];
    const float* nw1  = (const float*)d_in[5];
    const float* nb1  = (const float*)d_in[6];
    const float* g1ws = (const float*)d_in[7];
    const float* g1bs = (const float*)d_in[8];
    const float* g1wd = (const float*)d_in[9];
    const float* g1bd = (const float*)d_in[10];
    const float* g1a  = (const float*)d_in[11];
    const float* g2ws = (const float*)d_in[12];
    const float* g2bs = (const float*)d_in[13];
    const float* g2wd = (const float*)d_in[14];
    const float* g2bd = (const float*)d_in[15];
    const float* g2a  = (const float*)d_in[16];
    const float* ew0  = (const float*)d_in[17];
    const float* eb0  = (const float*)d_in[18];
    const float* ew1  = (const float*)d_in[19];
    const float* eb1  = (const float*)d_in[20];
    const float* ew2  = (const float*)d_in[21];
    const float* eb2  = (const float*)d_in[22];
    float* out = (float*)d_out;

    float* wsF = (float*)d_ws;
    float* h1  = wsF;                       // 20000*128
    float* g2o = wsF + 2560000;             // 20000*256
    float* fsb = wsF + 7680000;             // 20000*128 used (NodeMLP scratch)
    float* fdb = wsF + 12800000;            // 20000*256
    float* g1o = wsF + 17920000;            // 20000*256
    // fp16 S/D overlay fsb / fdb regions (dead by S/D-fc time)
    _Float16* Sh = (_Float16*)(wsF + 7680000);
    _Float16* Dh = (_Float16*)(wsF + 12800000);
    _Float16* fsh = (_Float16*)(wsF + 23040000);   // 20000*256 fp16
    int* wsI     = (int*)(wsF + 28160000);
    int* row_off = wsI;                     // [0, 20016)
    int* cursor  = wsI + 20016;             // [20016, 40032)
    int* eidx    = wsI + 40032;             // [40032, 360032)
    int* srcs    = wsI + 360032;            // [360032, 680032)
    // ---- B-fragment pack region (tail), hi only ----
    _Float16* pkH = (_Float16*)((char*)d_ws + 115361280);

    // ---- CSR hist + weight prepack (merged, independent work) ----
    hipMemsetAsync(cursor, 0, N_NODES * sizeof(int), stream);
    PackIn pin{ew1, g1ws, g1wd, g2ws, g2wd, ew0, nw0, nw1, pkH, dst, cursor};
    hist_prepack_kernel<<<HIST_BLK + PACK_BLK, 256, 0, stream>>>(pin);
    scan_all_kernel<<<1, 1024, 0, stream>>>(cursor, row_off, cursor);

    // ---- merged: scatter || (NodeMLP fc1 + G1 fc) ----
    {   LinOut lo{};
        lo.y[0] = fsb;        lo.b[0] = nb0;        lo.ldy[0] = 128; lo.relu[0] = 1;
        lo.yh[1] = fsh;       lo.b[1] = g1bs;       lo.ldy[1] = 256;
        lo.yh[2] = fsh + 128; lo.b[2] = g1bs + 128; lo.ldy[2] = 256;
        lo.y[3] = fdb;        lo.b[3] = g1bd;       lo.ldy[3] = 256;
        lo.y[4] = fdb + 128;  lo.b[4] = g1bd + 128; lo.ldy[4] = 256;
        scatter_xfc_kernel<<<1250 + 3125, 256, 0, stream>>>(
            src, dst, cursor, eidx, srcs, x, pkH + OFF_X * 8, lo); }

    // ---- merged: GAT layer-1 attention || NodeMLP fc2 ----
    {   LinOut lo2{};
        lo2.y[0] = h1; lo2.b[0] = nb1; lo2.ldy[0] = 128; lo2.relu[0] = 1;
        gat1_fc2_kernel<<<5000 + 625, 256, 0, stream>>>(
            fsh, fdb, g1a, row_off, srcs, g1o, fsb, pkH + OFF_N1 * 8, lo2); }

    // ---- GATv2 layer 2 fc (128-row blocks) + attention ----
    {   LinOut lo{};
        lo.yh[0] = fsh; lo.b[0] = g2bs; lo.ldy[0] = 256;
        lo.y[1] = fdb;  lo.b[1] = g2bd; lo.ldy[1] = 256;
        mfma_linear2_kernel<256, 8, 4, 256, 256, 256, 2, 8192>
            <<<dim3(157, 2), 256, 0, stream>>>(g1o, g1o, pkH + OFF_G2S * 8, lo, N_NODES); }
    gat_fused_kernel<<<5000, 256, 0, stream>>>(fsh, fdb, g2a, row_off, srcs, g2o);

    // ---- fused S|D precompute, fp16 output (128-row blocks) ----
    {   LinOut lo{};
        lo.yh[0] = Sh;       lo.ldy[0] = 512;
        lo.yh[1] = Sh + 256; lo.ldy[1] = 512;
        lo.yh[2] = Dh;       lo.b[2] = eb0;       lo.ldy[2] = 512;
        lo.yh[3] = Dh + 256; lo.b[3] = eb0 + 256; lo.ldy[3] = 512;
        mfma_linear2_kernel<384, 8, 4, 128, 128, 256, 2, 12288>
            <<<dim3(157, 4), 256, 0, stream>>>(h1, g2o, pkH + OFF_SW0 * 8, lo, N_NODES); }

    // ---- fused EdgeMLP v9 (8 waves/block, 2x occupancy) ----
    edge_mlp9_kernel<<<N_EDGES / 128, 512, 0, stream>>>(Sh, Dh, srcs, eidx, dst,
                                                        pkH + OFF_W1 * 8,
                                                        eb1, ew2, eb2, out);
}

// Round 15
// 520.479 us; speedup vs baseline: 1.0739x; 1.0739x over previous
//
#include <hip/hip_runtime.h>
#include <hip/hip_bf16.h>

// ---------------------------------------------------------------------------
// EdgePredModel: NodeMLP + 2x GATv2 + EdgeMLP.
// R15: consolidate — edge kernel reverted to mlp7 (R10/R13 winner: LDS-staged
//      B, fp16 S/D, single-product; occupancy is NOT the edge constraint,
//      L1/LDS byte-issue is — mlp8/mlp9 post-mortems). Node side keeps R14's
//      gains: 4-edge-ILP gat, scatter||x-fc, gat1||fc2, merged hist/prepack.
// ---------------------------------------------------------------------------
constexpr int N_NODES = 20000;
constexpr int N_EDGES = 320000;

typedef _Float16 half8 __attribute__((ext_vector_type(8)));
typedef _Float16 half4 __attribute__((ext_vector_type(4)));
typedef float    f32x16 __attribute__((ext_vector_type(16)));

__device__ __forceinline__ float lrelu(float x) { return x > 0.f ? x : 0.2f * x; }

// ------------------------------ CSR build ---------------------------------
// single-block exclusive scan of 20000 counts -> row_off, cursor
__global__ void scan_all_kernel(const int* __restrict__ counts,
                                int* __restrict__ row_off, int* __restrict__ cursor) {
    __shared__ int ps[1024];
    const int t = threadIdx.x;
    const int base = t * 20;
    int loc[20];
    int sum = 0;
#pragma unroll
    for (int i = 0; i < 20; ++i) {
        const int idx = base + i;
        const int v = (idx < N_NODES) ? counts[idx] : 0;
        loc[i] = sum;
        sum += v;
    }
    ps[t] = sum;
    __syncthreads();
    for (int off = 1; off < 1024; off <<= 1) {
        const int v = (t >= off) ? ps[t - off] : 0;
        __syncthreads();
        ps[t] += v;
        __syncthreads();
    }
    const int ex = ps[t] - sum;     // exclusive prefix of this thread's chunk
#pragma unroll
    for (int i = 0; i < 20; ++i) {
        const int idx = base + i;
        if (idx < N_NODES) {
            row_off[idx] = ex + loc[i];
            cursor[idx]  = ex + loc[i];
        }
    }
    if (t == 0) row_off[N_NODES] = N_EDGES;
}

// --------------------- W prepack into B-fragments (hi only) ----------------
template <int K, int M>
__device__ __forceinline__ void pack_one(int idx, const float* __restrict__ W,
                                         int r1, int k1, int r2, int joff, int ldw,
                                         _Float16* __restrict__ H) {
    const int l  = idx & 63;
    const int t  = (idx >> 6) % (M / 32);
    const int s  = (idx >> 6) / (M / 32);
    const int j  = joff + t * 32 + (l & 31);
    const int kb = s * 16 + (l >> 5) * 8;
    half8 vh;
#pragma unroll
    for (int i = 0; i < 8; ++i) {
        const int k    = kb + i;
        const int rrow = (k < k1) ? (r1 + k) : (r2 + (k - k1));
        vh[i] = (_Float16)W[(size_t)rrow * ldw + j];
    }
    reinterpret_cast<half8*>(H)[idx] = vh;
}

// segment offsets in half8 units
constexpr int OFF_W1  = 0;        // ew1  512x256 -> 16384
constexpr int OFF_G2S = 16384;    // g2ws 256x256 ->  8192
constexpr int OFF_G2D = 24576;    // g2wd
constexpr int OFF_SW0 = 32768;    // ew0-S cols 0-255 -> 12288
constexpr int OFF_SW1 = 45056;
constexpr int OFF_DW0 = 57344;
constexpr int OFF_DW1 = 69632;
constexpr int OFF_N1  = 81920;    // nw1 128x128 -> 2048
constexpr int OFF_X   = 83968;    // 5 x 1024: nw0 | g1ws(2 segs) | g1wd(2 segs)
constexpr int PACK_TOT = 89088;   // total half8
constexpr int PACK_BLK = (PACK_TOT + 255) / 256;   // 348
constexpr int HIST_BLK = 1250;

struct PackIn {
    const float *ew1, *g1ws, *g1wd, *g2ws, *g2wd, *ew0, *nw0, *nw1;
    _Float16 *H;
    const int* dst;
    int* counts;
};

// merged: blocks [0,HIST_BLK) do dst-histogram; rest do weight prepack
__global__ void hist_prepack_kernel(PackIn a) {
    if (blockIdx.x < HIST_BLK) {
        const int e = blockIdx.x * 256 + threadIdx.x;
        if (e < N_EDGES) atomicAdd(&a.counts[a.dst[e]], 1);
        return;
    }
    const int idx = (blockIdx.x - HIST_BLK) * 256 + threadIdx.x;
    if (idx >= PACK_TOT) return;
    _Float16* H = a.H;
    if (idx < OFF_G2S)
        pack_one<512, 256>(idx - OFF_W1, a.ew1, 0, 512, 0, 0, 256, H + OFF_W1 * 8);
    else if (idx < OFF_G2D)
        pack_one<256, 256>(idx - OFF_G2S, a.g2ws, 0, 256, 0, 0, 256, H + OFF_G2S * 8);
    else if (idx < OFF_SW0)
        pack_one<256, 256>(idx - OFF_G2D, a.g2wd, 0, 256, 0, 0, 256, H + OFF_G2D * 8);
    else if (idx < OFF_SW1)
        pack_one<384, 256>(idx - OFF_SW0, a.ew0, 0, 128, 256, 0, 512, H + OFF_SW0 * 8);
    else if (idx < OFF_DW0)
        pack_one<384, 256>(idx - OFF_SW1, a.ew0, 0, 128, 256, 256, 512, H + OFF_SW1 * 8);
    else if (idx < OFF_DW1)
        pack_one<384, 256>(idx - OFF_DW0, a.ew0, 128, 128, 512, 0, 512, H + OFF_DW0 * 8);
    else if (idx < OFF_N1)
        pack_one<384, 256>(idx - OFF_DW1, a.ew0, 128, 128, 512, 256, 512, H + OFF_DW1 * 8);
    else if (idx < OFF_X)
        pack_one<128, 128>(idx - OFF_N1, a.nw1, 0, 128, 0, 0, 128, H + OFF_N1 * 8);
    else {
        const int xi  = idx - OFF_X;
        const int seg = xi >> 10, r = xi & 1023;
        const int sb  = OFF_X + seg * 1024;
        if (seg == 0)
            pack_one<64, 128>(r, a.nw0, 0, 64, 0, 0, 128, H + sb * 8);
        else if (seg <= 2)
            pack_one<64, 128>(r, a.g1ws, 0, 64, 0, (seg - 1) * 128, 256, H + sb * 8);
        else
            pack_one<64, 128>(r, a.g1wd, 0, 64, 0, (seg - 3) * 128, 256, H + sb * 8);
    }
}

// ----------------------- split-fp16 MFMA node linear -----------------------
// 2-product: y = (xh + xl) @ Wh. Per-jb outputs fp32 y and/or fp16 yh.
struct LinOut { float* y[6]; const float* b[6]; _Float16* yh[6]; int ldy[6]; int relu[6]; };

template <int K, int TJ, int WR, int K1, int LD1, int LD2, int SEG>
__device__ __forceinline__ void linear_body(
    int bx, int jb,
    const float* __restrict__ X1, const float* __restrict__ X2,
    const _Float16* __restrict__ BHp, const LinOut& lo, int N) {
    constexpr int WC    = 4 / WR;
    constexpr int TILES = WC * TJ;
    const int tid = threadIdx.x;
    const int wv  = tid >> 6, l = tid & 63;
    const int rg  = (WR == 1) ? 0 : ((WR == 4) ? wv : (wv & 1));
    const int cg  = (WR == 1) ? wv : ((WR == 4) ? 0 : (wv >> 1));
    const int m   = l & 31, h = l >> 5;
    const int row = bx * (32 * WR) + rg * 32 + m;
    const int ar  = (row < N) ? row : (N - 1);
    const float* __restrict__ xr1 = X1 + (size_t)ar * LD1;
    const float* __restrict__ xr2 = X2 + (size_t)ar * LD2;
    const half8* __restrict__ BH = reinterpret_cast<const half8*>(BHp) + (size_t)jb * SEG;
    const float* __restrict__ bp = lo.b[jb];
    float* __restrict__ Y = lo.y[jb];
    _Float16* __restrict__ Yh = lo.yh[jb];
    const int ldy = lo.ldy[jb];
    const int rel = lo.relu[jb];

    f32x16 acc[TJ];
#pragma unroll
    for (int jt = 0; jt < TJ; ++jt) {
        const float bv = bp ? bp[cg * TJ * 32 + jt * 32 + m] : 0.f;
#pragma unroll
        for (int r = 0; r < 16; ++r) acc[jt][r] = bv;
    }

    const int kf = h * 8;
    const float* pf = (kf < K1) ? (xr1 + kf) : (xr2 + (kf - K1));
    float4 xa = *reinterpret_cast<const float4*>(pf);
    float4 xb = *reinterpret_cast<const float4*>(pf + 4);

    for (int s = 0; s < K / 16; ++s) {
        const float xs[8] = {xa.x, xa.y, xa.z, xa.w, xb.x, xb.y, xb.z, xb.w};
        if (s + 1 < K / 16) {
            const int kn = (s + 1) * 16 + h * 8;
            const float* pn = (kn < K1) ? (xr1 + kn) : (xr2 + (kn - K1));
            xa = *reinterpret_cast<const float4*>(pn);
            xb = *reinterpret_cast<const float4*>(pn + 4);
        }
        half8 ah, al;
#pragma unroll
        for (int i = 0; i < 8; ++i) {
            const _Float16 hi = (_Float16)xs[i];
            ah[i] = hi;
            al[i] = (_Float16)(xs[i] - (float)hi);
        }
#pragma unroll
        for (int jt = 0; jt < TJ; ++jt) {
            const int fi = (s * TILES + cg * TJ + jt) * 64 + l;
            const half8 bh = BH[fi];
            acc[jt] = __builtin_amdgcn_mfma_f32_32x32x16_f16(ah, bh, acc[jt], 0, 0, 0);
            acc[jt] = __builtin_amdgcn_mfma_f32_32x32x16_f16(al, bh, acc[jt], 0, 0, 0);
        }
    }

    const int rbase = bx * (32 * WR) + rg * 32;
#pragma unroll
    for (int jt = 0; jt < TJ; ++jt) {
        const int j = cg * TJ * 32 + jt * 32 + m;
#pragma unroll
        for (int r = 0; r < 16; ++r) {
            const int orow = rbase + (r & 3) + 8 * (r >> 2) + 4 * h;
            if (orow < N) {
                float v = acc[jt][r];
                if (rel) v = fmaxf(v, 0.f);
                if (Y)  Y[(size_t)orow * ldy + j] = v;
                if (Yh) Yh[(size_t)orow * ldy + j] = (_Float16)v;
            }
        }
    }
}

template <int K, int TJ, int WR, int K1, int LD1, int LD2, int MINW, int SEG>
__global__ __launch_bounds__(256, MINW) void mfma_linear2_kernel(
    const float* __restrict__ X1, const float* __restrict__ X2,
    const _Float16* __restrict__ BHp, LinOut lo, int N) {
    linear_body<K, TJ, WR, K1, LD1, LD2, SEG>(blockIdx.x, blockIdx.y, X1, X2, BHp, lo, N);
}

// --------------------------- fused GATv2 layer -----------------------------
// No online max (logits bounded); 4-edge ILP pipeline.
__device__ __forceinline__ void gat_body(int n, const _Float16* __restrict__ fsh,
                                         const float* __restrict__ fd,
                                         const float* __restrict__ attn,
                                         const int* __restrict__ row_off,
                                         const int* __restrict__ srcs,
                                         float* __restrict__ outp) {
    const int l = threadIdx.x & 63;
    const int base = (l >> 5) * 128 + (l & 31) * 4;    // h*128 + d
    const float4 fdv = *reinterpret_cast<const float4*>(&fd[n * 256 + base]);
    const float4 av  = *reinterpret_cast<const float4*>(&attn[base]);
    const int s0 = row_off[n], s1 = row_off[n + 1];

    auto LD = [&](int k) {
        return *reinterpret_cast<const half4*>(&fsh[(size_t)srcs[k] * 256 + base]);
    };
    auto LOGIT = [&](const float4& v) {
        float p = lrelu(v.x + fdv.x) * av.x;
        p = fmaf(lrelu(v.y + fdv.y), av.y, p);
        p = fmaf(lrelu(v.z + fdv.z), av.z, p);
        p = fmaf(lrelu(v.w + fdv.w), av.w, p);
        return p;
    };

    float lsum = 0.f;
    float4 acc = {0.f, 0.f, 0.f, 0.f};
    half4 c[4], nx[4];
#pragma unroll
    for (int k = 0; k < 4; ++k) { c[k] = half4{0, 0, 0, 0}; nx[k] = half4{0, 0, 0, 0}; }
    int i = s0;
#pragma unroll
    for (int k = 0; k < 4; ++k) if (i + k < s1) c[k] = LD(i + k);
#pragma unroll
    for (int k = 0; k < 4; ++k) if (i + 4 + k < s1) nx[k] = LD(i + 4 + k);

    for (; i + 3 < s1; i += 4) {
        float4 v[4];
#pragma unroll
        for (int k = 0; k < 4; ++k)
            v[k] = float4{(float)c[k].x, (float)c[k].y, (float)c[k].z, (float)c[k].w};
#pragma unroll
        for (int k = 0; k < 4; ++k) {
            c[k] = nx[k];
            if (i + 8 + k < s1) nx[k] = LD(i + 8 + k);
        }
        float p[4];
#pragma unroll
        for (int k = 0; k < 4; ++k) p[k] = LOGIT(v[k]);
#pragma unroll
        for (int off = 1; off < 32; off <<= 1)
#pragma unroll
            for (int k = 0; k < 4; ++k) p[k] += __shfl_xor(p[k], off);
        float w[4];
#pragma unroll
        for (int k = 0; k < 4; ++k) w[k] = __expf(p[k]);
        lsum += (w[0] + w[1]) + (w[2] + w[3]);
#pragma unroll
        for (int k = 0; k < 4; ++k) {
            acc.x = fmaf(w[k], v[k].x, acc.x);
            acc.y = fmaf(w[k], v[k].y, acc.y);
            acc.z = fmaf(w[k], v[k].z, acc.z);
            acc.w = fmaf(w[k], v[k].w, acc.w);
        }
    }
    for (int k = 0; i < s1; ++i, ++k) {                  // tail (0..3 edges, in c[])
        const float4 v = {(float)c[k].x, (float)c[k].y, (float)c[k].z, (float)c[k].w};
        float p = LOGIT(v);
#pragma unroll
        for (int off = 1; off < 32; off <<= 1) p += __shfl_xor(p, off);
        const float w = __expf(p);
        lsum += w;
        acc.x = fmaf(w, v.x, acc.x);
        acc.y = fmaf(w, v.y, acc.y);
        acc.z = fmaf(w, v.z, acc.z);
        acc.w = fmaf(w, v.w, acc.w);
    }
    const float inv = (s1 > s0) ? 1.f / lsum : 0.f;
    float4 o;
    o.x = fmaxf(acc.x * inv, 0.f);
    o.y = fmaxf(acc.y * inv, 0.f);
    o.z = fmaxf(acc.z * inv, 0.f);
    o.w = fmaxf(acc.w * inv, 0.f);
    *reinterpret_cast<float4*>(&outp[n * 256 + base]) = o;
}

__global__ __launch_bounds__(256, 4) void gat_fused_kernel(
    const _Float16* __restrict__ fsh, const float* __restrict__ fd,
    const float* __restrict__ attn, const int* __restrict__ row_off,
    const int* __restrict__ srcs, float* __restrict__ outp) {
    const int n = blockIdx.x * 4 + (threadIdx.x >> 6);
    if (n < N_NODES) gat_body(n, fsh, fd, attn, row_off, srcs, outp);
}

// ---------------- merged: scatter (CSR) || x-fc (5 segments) ---------------
__global__ __launch_bounds__(256, 4) void scatter_xfc_kernel(
    const int* __restrict__ src, const int* __restrict__ dst,
    int* __restrict__ cursor, int* __restrict__ eidx, int* __restrict__ srcs,
    const float* __restrict__ x, const _Float16* __restrict__ BH, LinOut lo) {
    if (blockIdx.x < 1250) {
        const int e = blockIdx.x * 256 + threadIdx.x;
        if (e < N_EDGES) {
            const int p = atomicAdd(&cursor[dst[e]], 1);
            eidx[p] = e;
            srcs[p] = src[e];
        }
        return;
    }
    const int bx = blockIdx.x - 1250;                 // [0, 3125)
    linear_body<64, 1, 1, 64, 64, 64, 1024>(bx % 625, bx / 625, x, x, BH, lo, N_NODES);
}

// ---------------- merged: GAT layer-1 || NodeMLP fc2 -----------------------
__global__ __launch_bounds__(256, 4) void gat1_fc2_kernel(
    const _Float16* __restrict__ fsh, const float* __restrict__ fd,
    const float* __restrict__ attn, const int* __restrict__ row_off,
    const int* __restrict__ srcs, float* __restrict__ outp,
    const float* __restrict__ fsb, const _Float16* __restrict__ BHn1, LinOut lo2) {
    if (blockIdx.x < 5000) {
        const int n = blockIdx.x * 4 + (threadIdx.x >> 6);
        if (n < N_NODES) gat_body(n, fsh, fd, attn, row_off, srcs, outp);
        return;
    }
    linear_body<128, 1, 1, 128, 128, 128, 0>(blockIdx.x - 5000, 0, fsb, fsb, BHn1,
                                             lo2, N_NODES);
}

// ------------------------------ fused EdgeMLP v7 ---------------------------
// (R10/R13 winner, verbatim) fp16 S/D gather + single-product MFMA; B hi
// double-buffered in 16 KB LDS (staging shared by all 4 waves).
__global__ __launch_bounds__(256, 2) void edge_mlp7_kernel(
    const _Float16* __restrict__ S, const _Float16* __restrict__ Dn,
    const int* __restrict__ srcs, const int* __restrict__ eidx,
    const int* __restrict__ dstf,
    const _Float16* __restrict__ WpH,
    const float* __restrict__ b1, const float* __restrict__ w2,
    const float* __restrict__ b2, float* __restrict__ out) {
    __shared__ __align__(16) _Float16 Bs[2][8][512];   // 16 KB
    const int tid = threadIdx.x;
    const int wv  = tid >> 6, l = tid & 63;
    const int m   = l & 31, h = l >> 5;
    const int e0  = blockIdx.x * 128;
    const int slot = e0 + wv * 32 + m;
    const _Float16* __restrict__ Srow = S  + (size_t)srcs[slot] * 512;
    const _Float16* __restrict__ Drow = Dn + (size_t)dstf[eidx[slot]] * 512;

    f32x16 acc[8];
#pragma unroll
    for (int jt = 0; jt < 8; ++jt) {
        const float bv = b1[jt * 32 + m];
#pragma unroll
        for (int r = 0; r < 16; ++r) acc[jt][r] = bv;
    }

    // stage B(s=0) hi into buf 0: wave wv stages chunks 2wv, 2wv+1
#pragma unroll
    for (int c = 0; c < 2; ++c) {
        const int jt = wv * 2 + c;
        *reinterpret_cast<float4*>(&Bs[0][jt][l * 8]) =
            *reinterpret_cast<const float4*>(WpH + ((size_t)jt * 64 + l) * 8);
    }
    // x prefetch s=0 (one half8 each covers the full k-octet)
    half8 sv = *reinterpret_cast<const half8*>(Srow + h * 8);
    half8 dv = *reinterpret_cast<const half8*>(Drow + h * 8);
    __syncthreads();

    for (int s = 0; s < 32; ++s) {
        const int buf = s & 1;
        float4 bst[2];
        if (s < 31) {                        // B-hi stage loads for s+1
#pragma unroll
            for (int c = 0; c < 2; ++c) {
                const int jt = wv * 2 + c;
                bst[c] = *reinterpret_cast<const float4*>(
                    WpH + ((size_t)((s + 1) * 8 + jt) * 64 + l) * 8);
            }
        }
        half8 xh;
#pragma unroll
        for (int i = 0; i < 8; ++i) {
            const _Float16 t = sv[i] + dv[i];
            xh[i] = t > (_Float16)0.f ? t : (_Float16)0.f;
        }
        if (s < 31) {                        // prefetch next x k-octet
            const int ko = (s + 1) * 16 + h * 8;
            sv = *reinterpret_cast<const half8*>(Srow + ko);
            dv = *reinterpret_cast<const half8*>(Drow + ko);
        }
#pragma unroll
        for (int jt = 0; jt < 8; ++jt) {
            const half8 bh = *reinterpret_cast<const half8*>(&Bs[buf][jt][l * 8]);
            acc[jt] = __builtin_amdgcn_mfma_f32_32x32x16_f16(xh, bh, acc[jt], 0, 0, 0);
        }
        if (s < 31) {
#pragma unroll
            for (int c = 0; c < 2; ++c) {
                const int jt = wv * 2 + c;
                *reinterpret_cast<float4*>(&Bs[buf ^ 1][jt][l * 8]) = bst[c];
            }
        }
        __syncthreads();
    }

    // ---- layer-2 fold + 32-lane reduce + scatter store ----
    float part[16];
#pragma unroll
    for (int r = 0; r < 16; ++r) part[r] = 0.f;
#pragma unroll
    for (int jt = 0; jt < 8; ++jt) {
        const float w2v = w2[jt * 32 + m];
#pragma unroll
        for (int r = 0; r < 16; ++r)
            part[r] = fmaf(fmaxf(acc[jt][r], 0.f), w2v, part[r]);
    }
#pragma unroll
    for (int off = 1; off < 32; off <<= 1)
#pragma unroll
        for (int r = 0; r < 16; ++r) part[r] += __shfl_xor(part[r], off);
    if (m == 0) {
        const float b2v = b2[0];
#pragma unroll
        for (int r = 0; r < 16; ++r) {
            const int row = (r & 3) + 8 * (r >> 2) + 4 * h;
            out[eidx[e0 + wv * 32 + row]] = part[r] + b2v;
        }
    }
}

// ------------------------------ launch ------------------------------------
extern "C" void kernel_launch(void* const* d_in, const int* in_sizes, int n_in,
                              void* d_out, int out_size, void* d_ws, size_t ws_size,
                              hipStream_t stream) {
    (void)in_sizes; (void)n_in; (void)out_size; (void)ws_size;
    const float* x    = (const float*)d_in[0];
    const int*   src  = (const int*)d_in[1];
    const int*   dst  = (const int*)d_in[2];
    const float* nw0  = (const float*)d_in[3];
    const float* nb0  = (const float*)d_in[4];
    const float* nw1  = (const float*)d_in[5];
    const float* nb1  = (const float*)d_in[6];
    const float* g1ws = (const float*)d_in[7];
    const float* g1bs = (const float*)d_in[8];
    const float* g1wd = (const float*)d_in[9];
    const float* g1bd = (const float*)d_in[10];
    const float* g1a  = (const float*)d_in[11];
    const float* g2ws = (const float*)d_in[12];
    const float* g2bs = (const float*)d_in[13];
    const float* g2wd = (const float*)d_in[14];
    const float* g2bd = (const float*)d_in[15];
    const float* g2a  = (const float*)d_in[16];
    const float* ew0  = (const float*)d_in[17];
    const float* eb0  = (const float*)d_in[18];
    const float* ew1  = (const float*)d_in[19];
    const float* eb1  = (const float*)d_in[20];
    const float* ew2  = (const float*)d_in[21];
    const float* eb2  = (const float*)d_in[22];
    float* out = (float*)d_out;

    float* wsF = (float*)d_ws;
    float* h1  = wsF;                       // 20000*128
    float* g2o = wsF + 2560000;             // 20000*256
    float* fsb = wsF + 7680000;             // 20000*128 used (NodeMLP scratch)
    float* fdb = wsF + 12800000;            // 20000*256
    float* g1o = wsF + 17920000;            // 20000*256
    // fp16 S/D overlay fsb / fdb regions (dead by S/D-fc time)
    _Float16* Sh = (_Float16*)(wsF + 7680000);
    _Float16* Dh = (_Float16*)(wsF + 12800000);
    _Float16* fsh = (_Float16*)(wsF + 23040000);   // 20000*256 fp16
    int* wsI     = (int*)(wsF + 28160000);
    int* row_off = wsI;                     // [0, 20016)
    int* cursor  = wsI + 20016;             // [20016, 40032)
    int* eidx    = wsI + 40032;             // [40032, 360032)
    int* srcs    = wsI + 360032;            // [360032, 680032)
    // ---- B-fragment pack region (tail), hi only ----
    _Float16* pkH = (_Float16*)((char*)d_ws + 115361280);

    // ---- CSR hist + weight prepack (merged, independent work) ----
    hipMemsetAsync(cursor, 0, N_NODES * sizeof(int), stream);
    PackIn pin{ew1, g1ws, g1wd, g2ws, g2wd, ew0, nw0, nw1, pkH, dst, cursor};
    hist_prepack_kernel<<<HIST_BLK + PACK_BLK, 256, 0, stream>>>(pin);
    scan_all_kernel<<<1, 1024, 0, stream>>>(cursor, row_off, cursor);

    // ---- merged: scatter || (NodeMLP fc1 + G1 fc) ----
    {   LinOut lo{};
        lo.y[0] = fsb;        lo.b[0] = nb0;        lo.ldy[0] = 128; lo.relu[0] = 1;
        lo.yh[1] = fsh;       lo.b[1] = g1bs;       lo.ldy[1] = 256;
        lo.yh[2] = fsh + 128; lo.b[2] = g1bs + 128; lo.ldy[2] = 256;
        lo.y[3] = fdb;        lo.b[3] = g1bd;       lo.ldy[3] = 256;
        lo.y[4] = fdb + 128;  lo.b[4] = g1bd + 128; lo.ldy[4] = 256;
        scatter_xfc_kernel<<<1250 + 3125, 256, 0, stream>>>(
            src, dst, cursor, eidx, srcs, x, pkH + OFF_X * 8, lo); }

    // ---- merged: GAT layer-1 attention || NodeMLP fc2 ----
    {   LinOut lo2{};
        lo2.y[0] = h1; lo2.b[0] = nb1; lo2.ldy[0] = 128; lo2.relu[0] = 1;
        gat1_fc2_kernel<<<5000 + 625, 256, 0, stream>>>(
            fsh, fdb, g1a, row_off, srcs, g1o, fsb, pkH + OFF_N1 * 8, lo2); }

    // ---- GATv2 layer 2 fc (128-row blocks) + attention ----
    {   LinOut lo{};
        lo.yh[0] = fsh; lo.b[0] = g2bs; lo.ldy[0] = 256;
        lo.y[1] = fdb;  lo.b[1] = g2bd; lo.ldy[1] = 256;
        mfma_linear2_kernel<256, 8, 4, 256, 256, 256, 2, 8192>
            <<<dim3(157, 2), 256, 0, stream>>>(g1o, g1o, pkH + OFF_G2S * 8, lo, N_NODES); }
    gat_fused_kernel<<<5000, 256, 0, stream>>>(fsh, fdb, g2a, row_off, srcs, g2o);

    // ---- fused S|D precompute, fp16 output (128-row blocks) ----
    {   LinOut lo{};
        lo.yh[0] = Sh;       lo.ldy[0] = 512;
        lo.yh[1] = Sh + 256; lo.ldy[1] = 512;
        lo.yh[2] = Dh;       lo.b[2] = eb0;       lo.ldy[2] = 512;
        lo.yh[3] = Dh + 256; lo.b[3] = eb0 + 256; lo.ldy[3] = 512;
        mfma_linear2_kernel<384, 8, 4, 128, 128, 256, 2, 12288>
            <<<dim3(157, 4), 256, 0, stream>>>(h1, g2o, pkH + OFF_SW0 * 8, lo, N_NODES); }

    // ---- fused EdgeMLP v7 (LDS-staged B, fp16 S/D, single-product) ----
    edge_mlp7_kernel<<<N_EDGES / 128, 256, 0, stream>>>(Sh, Dh, srcs, eidx, dst,
                                                        pkH + OFF_W1 * 8,
                                                        eb1, ew2, eb2, out);
}